// Round 15
// baseline (185.014 us; speedup 1.0000x reference)
//
#include <hip/hip_runtime.h>
#include <hip/hip_fp16.h>

#define BN 4
#define CN 256
#define PN 4096
#define QT 32
#define TSTR 264

typedef __attribute__((ext_vector_type(8))) short short8;
typedef __attribute__((ext_vector_type(8))) unsigned short ushort8;
typedef __attribute__((ext_vector_type(4))) unsigned short us4;
typedef __attribute__((ext_vector_type(4))) float f32x4;
typedef __attribute__((ext_vector_type(4))) unsigned int u32x4;
typedef unsigned int u32;

__device__ __forceinline__ unsigned short f2bf(float f) {
  u32 u = __builtin_bit_cast(u32, f);
  return (unsigned short)((u + 0x7fffu + ((u >> 16) & 1u)) >> 16);
}

__device__ __forceinline__ void async_copy16(const void* g, void* l) {
  __builtin_amdgcn_global_load_lds((const __attribute__((address_space(1))) u32*)g,
                                   (__attribute__((address_space(3))) u32*)l, 16, 0, 0);
}

// Frag-major layout (per batch, per 64-q block = 32 KB = 32 frags of 1024B):
//   frag F = nt*8 + kc; byte = F*1024 + (g*16+lr)*16 + j*2
//     <-> xn[q = qb*64 + nt*16 + lr][ch = kc*32 + g*8 + j]
// V frags q-PERMUTED: frag f = kk*16 + n2; byte = f*1024 + (g*16+lr)*16 + j*2
//     <-> V[q = kk*32 + perm(g*8+j)][c = n2*16 + lr]  (perm matches cvt_pk'd S order)
// QT=32 tile t = 16KB slice [t*16384, +16K) of both arrays.

// ---- fused k_nxgx: norms + xnK (frag-major bf16) + gxF (frag-major permuted V)
__global__ __launch_bounds__(256) void k_nxgx(const float* __restrict__ x,
                                              const float* __restrict__ Wm,
                                              const float* __restrict__ bias,
                                              unsigned short* __restrict__ xnK,
                                              unsigned short* __restrict__ gxF) {
  __shared__ unsigned short tl[64 * TSTR];
  __shared__ float red[4][64];
  __shared__ float mnl[64];
  const int b = blockIdx.y, qb = blockIdx.x;
  const int tid = threadIdx.x;
  const int tp = tid & 63, cg = tid >> 6;

  {
    const float* xp = x + ((size_t)b * CN + cg * 64) * PN + qb * 64 + tp;
    float v[64];
    float ss = 0.f;
#pragma unroll
    for (int i = 0; i < 64; ++i) {
      v[i] = xp[(size_t)i * PN];
      ss += v[i] * v[i];
    }
    red[cg][tp] = ss;
    __syncthreads();
    float nrm = sqrtf(red[0][tp] + red[1][tp] + red[2][tp] + red[3][tp]);
    float mn = fmaxf(nrm, 1e-8f);
    float rn = 1.f / mn;
    if (cg == 0) mnl[tp] = mn;
    unsigned int* tl32 = (unsigned int*)tl;
#pragma unroll
    for (int j = 0; j < 32; ++j) {
      unsigned int w = (unsigned int)f2bf(v[2 * j] * rn) |
                       ((unsigned int)f2bf(v[2 * j + 1] * rn) << 16);
      tl32[tp * (TSTR / 2) + cg * 32 + j] = w;
    }
    __syncthreads();
    char* dstb = (char*)xnK + (size_t)b * (PN * CN * 2) + (size_t)qb * 32768;
#pragma unroll
    for (int m = 0; m < 8; ++m) {
      int idx = m * 256 + tid;
      int F = idx >> 6, ln = idx & 63;
      int pl = (F >> 3) * 16 + (ln & 15);
      int ch = (F & 7) * 32 + (ln >> 4) * 8;
      ushort8 o = *(const ushort8*)(tl + pl * TSTR + ch);
      *(ushort8*)(dstb + (size_t)idx * 16) = o;
    }
  }

  const int wave = tid >> 6, lane = tid & 63;
  const int lr = lane & 15, g = lane >> 4;
  char* vbb = (char*)gxF + (size_t)b * (PN * CN * 2) + (size_t)qb * 32768;
#pragma unroll
  for (int mp = 0; mp < 2; ++mp) {
    short8 af[2][8];
#pragma unroll
    for (int mt = 0; mt < 2; ++mt) {
      const float* wr = Wm + (size_t)(wave * 64 + mp * 32 + mt * 16 + lr) * CN;
#pragma unroll
      for (int k = 0; k < 8; ++k) {
        const float* ap = wr + k * 32 + g * 8;
        short8 a;
#pragma unroll
        for (int j = 0; j < 8; ++j) a[j] = (short)f2bf(ap[j]);
        af[mt][k] = a;
      }
    }
    f32x4 acc[2][4];
#pragma unroll
    for (int mt = 0; mt < 2; ++mt)
#pragma unroll
      for (int n = 0; n < 4; ++n) acc[mt][n] = (f32x4){0.f, 0.f, 0.f, 0.f};
#pragma unroll
    for (int n = 0; n < 4; ++n)
#pragma unroll
      for (int k = 0; k < 8; ++k) {
        short8 bf = *(const short8*)((const char*)tl + (n * 16 + lr) * (TSTR * 2) + k * 64 + g * 16);
        acc[0][n] = __builtin_amdgcn_mfma_f32_16x16x32_bf16(af[0][k], bf, acc[0][n], 0, 0, 0);
        acc[1][n] = __builtin_amdgcn_mfma_f32_16x16x32_bf16(af[1][k], bf, acc[1][n], 0, 0, 0);
      }
#pragma unroll
    for (int n = 0; n < 4; ++n) {
      float mn = mnl[n * 16 + lr];
      int kk = n >> 1;
      int q32 = (n & 1) * 16 + lr;
      int gp = (q32 >> 2) & 3;
      int j = ((q32 >> 4) & 1) * 4 + (q32 & 3);
#pragma unroll
      for (int mt = 0; mt < 2; ++mt)
#pragma unroll
        for (int i = 0; i < 4; ++i) {
          int c = wave * 64 + mp * 32 + mt * 16 + g * 4 + i;
          float v = acc[mt][n][i] * mn + bias[c];
          *(unsigned short*)(vbb + ((kk * 16 + (c >> 4)) << 10) + (gp << 8) + ((c & 15) << 4) + (j << 1)) = f2bf(v);
        }
    }
  }
}

// ---- fused attention: 8-wave WG, M=16/wave, QT=32.
// K via LDS DMA (dbuf 2x16KB = 32KB -> 2 WGs/CU, 4 waves/SIMD).
// V via plain global b128 loads (frag-major coalesced) -> L1-broadcast across the
// 16 waves/CU, freeing the LDS read port. S stays in registers (q-permuted pack).
extern __shared__ char smem[];

__global__ __launch_bounds__(512, 4) void k_attn(const unsigned short* __restrict__ xnK,
                                                 const unsigned short* __restrict__ gxF,
                                                 __half* __restrict__ p0h, __half* __restrict__ p1h,
                                                 __half* __restrict__ p2h, __half* __restrict__ p3h,
                                                 int lq, int ntiles) {
  const int fid = blockIdx.x;
  const int b = fid & 3;
  const int qs = (fid >> 2) & ((1 << lq) - 1);
  const int pblk = fid >> (2 + lq);
  const int tid = threadIdx.x;
  const int wave = tid >> 6, lane = tid & 63, lr = lane & 15, g = lane >> 4;
  const int qt0 = (qs * (PN >> lq)) >> 5;
  const int p0 = pblk * 128 + wave * 16;
  __half* dsth = (qs == 0) ? p0h : (qs == 1) ? p1h : (qs == 2) ? p2h : p3h;

  const char* xb = (const char*)xnK + (size_t)b * (PN * CN * 2);
  const char* vg = (const char*)gxF + (size_t)b * (PN * CN * 2);
  const char* kq = xb + (size_t)qt0 * 16384;
  const char* vq = vg + (size_t)qt0 * 16384;
  const int ldst = tid * 16;
  const int lane16 = lane * 16;

  auto issue = [&](int t) {
    char* kb = smem + (t & 1) * 16384;
    const char* ks = kq + (size_t)t * 16384 + ldst;
    async_copy16(ks, kb + ldst);
    async_copy16(ks + 8192, kb + ldst + 8192);
  };

  issue(0);

  // Q hoist: 16 p-rows x 256 ch as B-operand frags
  short8 qf[8];
  {
    const char* qpb = xb + (size_t)(pblk * 2 + (wave >> 2)) * 32768;
    const int ntp = wave & 3;
#pragma unroll
    for (int k = 0; k < 8; ++k)
      qf[k] = *(const short8*)(qpb + ((ntp * 8 + k) << 10) + ((g * 16 + lr) << 4));
  }

  f32x4 yacc[16];
#pragma unroll
  for (int n = 0; n < 16; ++n) yacc[n] = (f32x4){0.f, 0.f, 0.f, 0.f};

  for (int t = 0; t < ntiles; ++t) {
    const char* kb = smem + (t & 1) * 16384;
    const char* vgt = vq + (size_t)t * 16384;

    // own K(t) DMA is a full tile old -> drain is near-free; barrier gates
    // K dbuf reuse; prefetch K(t+1) immediately after.
    asm volatile("s_waitcnt vmcnt(0)" ::: "memory");
    __builtin_amdgcn_s_barrier();
    if (t + 1 < ntiles) issue(t + 1);

    // QKT (swapped: D[q][p] = mfma(K, Q)), 16 MFMA; K from LDS
    f32x4 sacc0 = (f32x4){0.f, 0.f, 0.f, 0.f};
    f32x4 sacc1 = (f32x4){0.f, 0.f, 0.f, 0.f};
    __builtin_amdgcn_s_setprio(1);
#pragma unroll
    for (int k = 0; k < 8; ++k) {
      short8 kf0 = *(const short8*)(kb + k * 1024 + lane16);
      short8 kf1 = *(const short8*)(kb + (8 + k) * 1024 + lane16);
      sacc0 = __builtin_amdgcn_mfma_f32_16x16x32_bf16(kf0, qf[k], sacc0, 0, 0, 0);
      sacc1 = __builtin_amdgcn_mfma_f32_16x16x32_bf16(kf1, qf[k], sacc1, 0, 0, 0);
    }
    __builtin_amdgcn_s_setprio(0);

    // relu^2 -> q-permuted cvt_pk pack (S in registers)
    u32 pa[4];
#pragma unroll
    for (int h = 0; h < 2; ++h) {
      float a0 = fmaxf(sacc0[2 * h], 0.f); a0 *= a0;
      float a1 = fmaxf(sacc0[2 * h + 1], 0.f); a1 *= a1;
      asm("v_cvt_pk_bf16_f32 %0, %1, %2" : "=v"(pa[h]) : "v"(a0), "v"(a1));
      float b0 = fmaxf(sacc1[2 * h], 0.f); b0 *= b0;
      float b1 = fmaxf(sacc1[2 * h + 1], 0.f); b1 *= b1;
      asm("v_cvt_pk_bf16_f32 %0, %1, %2" : "=v"(pa[2 + h]) : "v"(b0), "v"(b1));
    }
    u32x4 w0 = {pa[0], pa[1], pa[2], pa[3]};
    short8 a0 = __builtin_bit_cast(short8, w0);

    // PV: V-frags straight from global (L1-broadcast), 16 MFMA
    __builtin_amdgcn_s_setprio(1);
#pragma unroll
    for (int n2 = 0; n2 < 16; ++n2) {
      short8 vf = *(const short8*)(vgt + n2 * 1024 + lane16);
      yacc[n2] = __builtin_amdgcn_mfma_f32_16x16x32_bf16(a0, vf, yacc[n2], 0, 0, 0);
    }
    __builtin_amdgcn_s_setprio(0);
  }
  asm volatile("s_waitcnt vmcnt(0)" ::: "memory");
  __builtin_amdgcn_s_barrier();

  // ---- epilogue: per-wave LDS transpose in 8 half-passes (32 c each, stride 20
  // floats -> aligned float4 reads), f16 partial stores.
  // yacc[n2][i] = y[p = p0 + g*4+i][c = n2*16 + lr]
  float* yl = (float*)(smem + wave * 2560);
  const int cq = lane >> 2, pq = (lane & 3) << 2;
#pragma unroll
  for (int cc = 0; cc < 8; ++cc) {
#pragma unroll
    for (int nn = 0; nn < 2; ++nn)
#pragma unroll
      for (int i = 0; i < 4; ++i)
        yl[(nn * 16 + lr) * 20 + g * 4 + i] = yacc[cc * 2 + nn][i];
#pragma unroll
    for (int i2 = 0; i2 < 2; ++i2) {
      int c = i2 * 16 + cq;
      float4 v = *(const float4*)(yl + c * 20 + pq);
      size_t off = ((size_t)b * CN + cc * 32 + c) * PN + p0 + pq;
      us4 h;
      h[0] = __builtin_bit_cast(unsigned short, __float2half(v.x));
      h[1] = __builtin_bit_cast(unsigned short, __float2half(v.y));
      h[2] = __builtin_bit_cast(unsigned short, __float2half(v.z));
      h[3] = __builtin_bit_cast(unsigned short, __float2half(v.w));
      *(us4*)(dsth + off) = h;
    }
  }
}

// ---- final reduction: out = sum of np f16 partials
__global__ void k_add(float* __restrict__ o, const uint2* __restrict__ a,
                      const uint2* __restrict__ bb, const uint2* __restrict__ c,
                      const uint2* __restrict__ d, int np, int n4) {
  int i = blockIdx.x * blockDim.x + threadIdx.x;
  int stride = gridDim.x * blockDim.x;
  float4* o4 = (float4*)o;
  for (; i < n4; i += stride) {
    uint2 ua = a[i];
    float2 f0 = __half22float2(__builtin_bit_cast(__half2, ua.x));
    float2 f1 = __half22float2(__builtin_bit_cast(__half2, ua.y));
    float4 r = {f0.x, f0.y, f1.x, f1.y};
    uint2 ub = bb[i];
    f0 = __half22float2(__builtin_bit_cast(__half2, ub.x));
    f1 = __half22float2(__builtin_bit_cast(__half2, ub.y));
    r.x += f0.x; r.y += f0.y; r.z += f1.x; r.w += f1.y;
    if (np > 2) {
      uint2 uc = c[i];
      f0 = __half22float2(__builtin_bit_cast(__half2, uc.x));
      f1 = __half22float2(__builtin_bit_cast(__half2, uc.y));
      r.x += f0.x; r.y += f0.y; r.z += f1.x; r.w += f1.y;
      uint2 ud = d[i];
      f0 = __half22float2(__builtin_bit_cast(__half2, ud.x));
      f1 = __half22float2(__builtin_bit_cast(__half2, ud.y));
      r.x += f0.x; r.y += f0.y; r.z += f1.x; r.w += f1.y;
    }
    o4[i] = r;
  }
}

extern "C" void kernel_launch(void* const* d_in, const int* in_sizes, int n_in,
                              void* d_out, int out_size, void* d_ws, size_t ws_size,
                              hipStream_t stream) {
  const float* x = (const float*)d_in[0];
  const float* Wm = (const float*)d_in[1];
  const float* bias = (const float*)d_in[2];
  float* out = (float*)d_out;

  char* ws = (char*)d_ws;
  unsigned short* xnK = (unsigned short*)ws;                        // 8 MB frag-major xn
  unsigned short* gxF = (unsigned short*)(ws + (size_t)8388608);    // 8 MB frag-major permuted V
  __half* p0 = (__half*)(ws + (size_t)16777216);                    // f16 partials x4 (8 MB each)
  __half* p1 = p0 + 4194304;
  __half* p2 = p1 + 4194304;
  __half* p3 = p2 + 4194304;
  const size_t need4 = 16777216ULL + 4ULL * 8388608ULL;

  hipFuncSetAttribute(reinterpret_cast<const void*>(k_attn),
                      hipFuncAttributeMaxDynamicSharedMemorySize, 32768);

  k_nxgx<<<dim3(PN / 64, BN), 256, 0, stream>>>(x, Wm, bias, xnK, gxF);
  if (ws_size >= need4) {
    k_attn<<<dim3(512), 512, 32768, stream>>>(xnK, gxF, p0, p1, p2, p3, 2, (PN / 4) / QT);
    k_add<<<dim3(1024), 256, 0, stream>>>(out, (const uint2*)p0, (const uint2*)p1,
                                          (const uint2*)p2, (const uint2*)p3, 4, BN * CN * PN / 4);
  } else {
    k_attn<<<dim3(256), 512, 32768, stream>>>(xnK, gxF, p0, p1, p0, p1, 1, (PN / 2) / QT);
    k_add<<<dim3(1024), 256, 0, stream>>>(out, (const uint2*)p0, (const uint2*)p1,
                                          (const uint2*)p0, (const uint2*)p1, 2, BN * CN * PN / 4);
  }
}

// Round 16
// 94.302 us; speedup vs baseline: 1.9619x; 1.9619x over previous
//
#include <hip/hip_runtime.h>
#include <hip/hip_fp16.h>

#define BN 4
#define CN 256
#define PN 4096
#define QT 64
#define TSTR 264

typedef __attribute__((ext_vector_type(8))) short short8;
typedef __attribute__((ext_vector_type(8))) unsigned short ushort8;
typedef __attribute__((ext_vector_type(4))) unsigned short us4;
typedef __attribute__((ext_vector_type(4))) float f32x4;
typedef __attribute__((ext_vector_type(4))) unsigned int u32x4;
typedef unsigned int u32;

__device__ __forceinline__ unsigned short f2bf(float f) {
  u32 u = __builtin_bit_cast(u32, f);
  return (unsigned short)((u + 0x7fffu + ((u >> 16) & 1u)) >> 16);
}

__device__ __forceinline__ void async_copy16(const void* g, void* l) {
  __builtin_amdgcn_global_load_lds((const __attribute__((address_space(1))) u32*)g,
                                   (__attribute__((address_space(3))) u32*)l, 16, 0, 0);
}

// Frag-major layout (per batch, per 64-q block = 32 KB = 32 frags of 1024B):
//   frag F = nt*8 + kc; byte = F*1024 + (g*16+lr)*16 + j*2
//     <-> xn[q = qb*64 + nt*16 + lr][ch = kc*32 + g*8 + j]
// V frags q-PERMUTED: frag f = kk*16 + n2; byte = f*1024 + (g*16+lr)*16 + j*2
//     <-> V[q = kk*32 + perm(g*8+j)][c = n2*16 + lr]  (perm matches cvt_pk'd S order)

// ---- fused k_nxgx: norms + xnK (frag-major bf16) + gxF (frag-major permuted V)
__global__ __launch_bounds__(256) void k_nxgx(const float* __restrict__ x,
                                              const float* __restrict__ Wm,
                                              const float* __restrict__ bias,
                                              unsigned short* __restrict__ xnK,
                                              unsigned short* __restrict__ gxF) {
  __shared__ unsigned short tl[64 * TSTR];
  __shared__ float red[4][64];
  __shared__ float mnl[64];
  const int b = blockIdx.y, qb = blockIdx.x;
  const int tid = threadIdx.x;
  const int tp = tid & 63, cg = tid >> 6;

  {
    const float* xp = x + ((size_t)b * CN + cg * 64) * PN + qb * 64 + tp;
    float v[64];
    float ss = 0.f;
#pragma unroll
    for (int i = 0; i < 64; ++i) {
      v[i] = xp[(size_t)i * PN];
      ss += v[i] * v[i];
    }
    red[cg][tp] = ss;
    __syncthreads();
    float nrm = sqrtf(red[0][tp] + red[1][tp] + red[2][tp] + red[3][tp]);
    float mn = fmaxf(nrm, 1e-8f);
    float rn = 1.f / mn;
    if (cg == 0) mnl[tp] = mn;
    unsigned int* tl32 = (unsigned int*)tl;
#pragma unroll
    for (int j = 0; j < 32; ++j) {
      unsigned int w = (unsigned int)f2bf(v[2 * j] * rn) |
                       ((unsigned int)f2bf(v[2 * j + 1] * rn) << 16);
      tl32[tp * (TSTR / 2) + cg * 32 + j] = w;
    }
    __syncthreads();
    char* dstb = (char*)xnK + (size_t)b * (PN * CN * 2) + (size_t)qb * 32768;
#pragma unroll
    for (int m = 0; m < 8; ++m) {
      int idx = m * 256 + tid;
      int F = idx >> 6, ln = idx & 63;
      int pl = (F >> 3) * 16 + (ln & 15);
      int ch = (F & 7) * 32 + (ln >> 4) * 8;
      ushort8 o = *(const ushort8*)(tl + pl * TSTR + ch);
      *(ushort8*)(dstb + (size_t)idx * 16) = o;
    }
  }

  // ---- phase B: gx = (W @ xn)*mn + bias, scattered to permuted V-frag layout
  const int wave = tid >> 6, lane = tid & 63;
  const int lr = lane & 15, g = lane >> 4;
  char* vbb = (char*)gxF + (size_t)b * (PN * CN * 2) + (size_t)qb * 32768;
#pragma unroll
  for (int mp = 0; mp < 2; ++mp) {
    short8 af[2][8];
#pragma unroll
    for (int mt = 0; mt < 2; ++mt) {
      const float* wr = Wm + (size_t)(wave * 64 + mp * 32 + mt * 16 + lr) * CN;
#pragma unroll
      for (int k = 0; k < 8; ++k) {
        const float* ap = wr + k * 32 + g * 8;
        short8 a;
#pragma unroll
        for (int j = 0; j < 8; ++j) a[j] = (short)f2bf(ap[j]);
        af[mt][k] = a;
      }
    }
    f32x4 acc[2][4];
#pragma unroll
    for (int mt = 0; mt < 2; ++mt)
#pragma unroll
      for (int n = 0; n < 4; ++n) acc[mt][n] = (f32x4){0.f, 0.f, 0.f, 0.f};
#pragma unroll
    for (int n = 0; n < 4; ++n)
#pragma unroll
      for (int k = 0; k < 8; ++k) {
        short8 bf = *(const short8*)((const char*)tl + (n * 16 + lr) * (TSTR * 2) + k * 64 + g * 16);
        acc[0][n] = __builtin_amdgcn_mfma_f32_16x16x32_bf16(af[0][k], bf, acc[0][n], 0, 0, 0);
        acc[1][n] = __builtin_amdgcn_mfma_f32_16x16x32_bf16(af[1][k], bf, acc[1][n], 0, 0, 0);
      }
#pragma unroll
    for (int n = 0; n < 4; ++n) {
      float mn = mnl[n * 16 + lr];
      int kk = n >> 1;
      int q32 = (n & 1) * 16 + lr;
      int gp = (q32 >> 2) & 3;
      int j = ((q32 >> 4) & 1) * 4 + (q32 & 3);
#pragma unroll
      for (int mt = 0; mt < 2; ++mt)
#pragma unroll
        for (int i = 0; i < 4; ++i) {
          int c = wave * 64 + mp * 32 + mt * 16 + g * 4 + i;
          float v = acc[mt][n][i] * mn + bias[c];
          *(unsigned short*)(vbb + ((kk * 16 + (c >> 4)) << 10) + (gp << 8) + ((c & 15) << 4) + (j << 1)) = f2bf(v);
        }
    }
  }
}

// ---- fused attention: r9/r12 proven loop (8-wave WG, M=32/wave, QT=64, 128KB dbuf,
// counted vmcnt(4)/(8), in-register q-permuted S). Epilogue: f16 partials.
extern __shared__ char smem[];

__global__ __launch_bounds__(512, 2) void k_attn(const unsigned short* __restrict__ xnK,
                                                 const unsigned short* __restrict__ gxF,
                                                 __half* __restrict__ p0h, __half* __restrict__ p1h,
                                                 __half* __restrict__ p2h, __half* __restrict__ p3h,
                                                 int lq, int ntiles) {
  const int fid = blockIdx.x;
  const int b = fid & 3;
  const int qs = (fid >> 2) & ((1 << lq) - 1);
  const int pblk = fid >> (2 + lq);
  const int tid = threadIdx.x;
  const int wave = tid >> 6, lane = tid & 63, lr = lane & 15, g = lane >> 4;
  const int qb0 = (qs * (PN >> lq)) >> 6;
  const int p0 = pblk * 256 + wave * 32;
  __half* dsth = (qs == 0) ? p0h : (qs == 1) ? p1h : (qs == 2) ? p2h : p3h;

  const char* xb = (const char*)xnK + (size_t)b * (PN * CN * 2);
  const char* vg = (const char*)gxF + (size_t)b * (PN * CN * 2);
  const char* kq = xb + (size_t)qb0 * 32768;
  const char* vq = vg + (size_t)qb0 * 32768;
  const int ldst = tid * 16;
  const int lane16 = lane * 16;

  auto issue_K = [&](int t) {
    char* kb = smem + (t & 1) * 65536;
    const char* s = kq + (size_t)t * 32768 + ldst;
#pragma unroll
    for (int j = 0; j < 4; ++j) async_copy16(s + j * 8192, kb + ldst + j * 8192);
  };
  auto issue_V = [&](int t) {
    char* vb = smem + (t & 1) * 65536 + 32768;
    const char* s = vq + (size_t)t * 32768 + ldst;
#pragma unroll
    for (int j = 0; j < 4; ++j) async_copy16(s + j * 8192, vb + ldst + j * 8192);
  };

  issue_K(0);
  issue_V(0);

  // Q hoist (32 p-rows x 256 ch as B-operand frags)
  short8 qf[2][8];
  {
    const char* qpb = xb + (size_t)(pblk * 4 + (wave >> 1)) * 32768;
#pragma unroll
    for (int mt = 0; mt < 2; ++mt) {
      int ntp = (wave & 1) * 2 + mt;
#pragma unroll
      for (int k = 0; k < 8; ++k)
        qf[mt][k] = *(const short8*)(qpb + ((ntp * 8 + k) << 10) + ((g * 16 + lr) << 4));
    }
  }

  f32x4 yacc[2][16];
#pragma unroll
  for (int mt = 0; mt < 2; ++mt)
#pragma unroll
    for (int n = 0; n < 16; ++n) yacc[mt][n] = (f32x4){0.f, 0.f, 0.f, 0.f};

  for (int t = 0; t < ntiles; ++t) {
    const char* kb = smem + (t & 1) * 65536;
    const char* vb = kb + 32768;

    asm volatile("s_waitcnt vmcnt(4)" ::: "memory");  // K(t) ready (V(t) in flight)
    __builtin_amdgcn_s_barrier();
    if (t + 1 < ntiles) { issue_K(t + 1); issue_V(t + 1); }

    // QKT (swapped: D[q][p] = mfma(K, Q)) + in-register S pack (q-permuted)
    u32 pa[2][2][4];  // [mt][kk][word]
#pragma unroll
    for (int nh = 0; nh < 2; ++nh) {
      f32x4 sacc[2][2];
#pragma unroll
      for (int n0 = 0; n0 < 2; ++n0)
#pragma unroll
        for (int mt = 0; mt < 2; ++mt) sacc[n0][mt] = (f32x4){0.f, 0.f, 0.f, 0.f};
      __builtin_amdgcn_s_setprio(1);
#pragma unroll
      for (int k = 0; k < 8; ++k) {
        short8 kf0 = *(const short8*)(kb + ((2 * nh) * 8 + k) * 1024 + lane16);
        short8 kf1 = *(const short8*)(kb + ((2 * nh + 1) * 8 + k) * 1024 + lane16);
        sacc[0][0] = __builtin_amdgcn_mfma_f32_16x16x32_bf16(kf0, qf[0][k], sacc[0][0], 0, 0, 0);
        sacc[0][1] = __builtin_amdgcn_mfma_f32_16x16x32_bf16(kf0, qf[1][k], sacc[0][1], 0, 0, 0);
        sacc[1][0] = __builtin_amdgcn_mfma_f32_16x16x32_bf16(kf1, qf[0][k], sacc[1][0], 0, 0, 0);
        sacc[1][1] = __builtin_amdgcn_mfma_f32_16x16x32_bf16(kf1, qf[1][k], sacc[1][1], 0, 0, 0);
      }
      __builtin_amdgcn_s_setprio(0);
#pragma unroll
      for (int mt = 0; mt < 2; ++mt)
#pragma unroll
        for (int n0 = 0; n0 < 2; ++n0)
#pragma unroll
          for (int h = 0; h < 2; ++h) {
            float a0 = fmaxf(sacc[n0][mt][2 * h], 0.f); a0 *= a0;
            float a1 = fmaxf(sacc[n0][mt][2 * h + 1], 0.f); a1 *= a1;
            u32 w;
            asm("v_cvt_pk_bf16_f32 %0, %1, %2" : "=v"(w) : "v"(a0), "v"(a1));
            pa[mt][nh][n0 * 2 + h] = w;
          }
    }

    if (t + 1 < ntiles) {
      asm volatile("s_waitcnt vmcnt(8)" ::: "memory");  // V(t) ready (t+1 in flight)
    } else {
      asm volatile("s_waitcnt vmcnt(0)" ::: "memory");
    }
    __builtin_amdgcn_s_barrier();

    // PV: Y[32p][256c] += S @ V (shared q-permutation)
#pragma unroll
    for (int kk = 0; kk < 2; ++kk) {
      u32x4 w0 = {pa[0][kk][0], pa[0][kk][1], pa[0][kk][2], pa[0][kk][3]};
      u32x4 w1 = {pa[1][kk][0], pa[1][kk][1], pa[1][kk][2], pa[1][kk][3]};
      short8 a0 = __builtin_bit_cast(short8, w0);
      short8 a1 = __builtin_bit_cast(short8, w1);
      __builtin_amdgcn_s_setprio(1);
#pragma unroll
      for (int n2 = 0; n2 < 16; ++n2) {
        short8 vf = *(const short8*)(vb + (kk * 16 + n2) * 1024 + lane16);
        yacc[0][n2] = __builtin_amdgcn_mfma_f32_16x16x32_bf16(a0, vf, yacc[0][n2], 0, 0, 0);
        yacc[1][n2] = __builtin_amdgcn_mfma_f32_16x16x32_bf16(a1, vf, yacc[1][n2], 0, 0, 0);
      }
      __builtin_amdgcn_s_setprio(0);
    }
  }
  __builtin_amdgcn_s_barrier();

  // ---- epilogue: per-wave LDS transpose, f16 partial stores
  // yacc[mt][n2][i] = y[p = p0 + mt*16 + g*4+i][c = n2*16 + lr]
  float* yl = (float*)(smem + wave * 16384);
  const int row8 = lane >> 3, p4 = (lane & 7) << 2;
#pragma unroll
  for (int cc = 0; cc < 4; ++cc) {
#pragma unroll
    for (int nn = 0; nn < 4; ++nn)
#pragma unroll
      for (int mt = 0; mt < 2; ++mt)
#pragma unroll
        for (int i = 0; i < 4; ++i)
          yl[(nn * 16 + lr) * 33 + mt * 16 + g * 4 + i] = yacc[mt][cc * 4 + nn][i];
#pragma unroll
    for (int r2 = 0; r2 < 8; ++r2) {
      int c = r2 * 8 + row8;
      float4 v = *(const float4*)(yl + c * 33 + p4);
      size_t off = ((size_t)b * CN + cc * 64 + c) * PN + p0 + p4;
      us4 h;
      h[0] = __builtin_bit_cast(unsigned short, __float2half(v.x));
      h[1] = __builtin_bit_cast(unsigned short, __float2half(v.y));
      h[2] = __builtin_bit_cast(unsigned short, __float2half(v.z));
      h[3] = __builtin_bit_cast(unsigned short, __float2half(v.w));
      *(us4*)(dsth + off) = h;
    }
  }
}

// ---- final reduction: out = sum of np f16 partials
__global__ void k_add(float* __restrict__ o, const uint2* __restrict__ a,
                      const uint2* __restrict__ bb, const uint2* __restrict__ c,
                      const uint2* __restrict__ d, int np, int n4) {
  int i = blockIdx.x * blockDim.x + threadIdx.x;
  int stride = gridDim.x * blockDim.x;
  float4* o4 = (float4*)o;
  for (; i < n4; i += stride) {
    uint2 ua = a[i];
    float2 f0 = __half22float2(__builtin_bit_cast(__half2, ua.x));
    float2 f1 = __half22float2(__builtin_bit_cast(__half2, ua.y));
    float4 r = {f0.x, f0.y, f1.x, f1.y};
    uint2 ub = bb[i];
    f0 = __half22float2(__builtin_bit_cast(__half2, ub.x));
    f1 = __half22float2(__builtin_bit_cast(__half2, ub.y));
    r.x += f0.x; r.y += f0.y; r.z += f1.x; r.w += f1.y;
    if (np > 2) {
      uint2 uc = c[i];
      f0 = __half22float2(__builtin_bit_cast(__half2, uc.x));
      f1 = __half22float2(__builtin_bit_cast(__half2, uc.y));
      r.x += f0.x; r.y += f0.y; r.z += f1.x; r.w += f1.y;
      uint2 ud = d[i];
      f0 = __half22float2(__builtin_bit_cast(__half2, ud.x));
      f1 = __half22float2(__builtin_bit_cast(__half2, ud.y));
      r.x += f0.x; r.y += f0.y; r.z += f1.x; r.w += f1.y;
    }
    o4[i] = r;
  }
}

extern "C" void kernel_launch(void* const* d_in, const int* in_sizes, int n_in,
                              void* d_out, int out_size, void* d_ws, size_t ws_size,
                              hipStream_t stream) {
  const float* x = (const float*)d_in[0];
  const float* Wm = (const float*)d_in[1];
  const float* bias = (const float*)d_in[2];
  float* out = (float*)d_out;

  char* ws = (char*)d_ws;
  unsigned short* xnK = (unsigned short*)ws;                        // 8 MB frag-major xn
  unsigned short* gxF = (unsigned short*)(ws + (size_t)8388608);    // 8 MB frag-major permuted V
  __half* p0 = (__half*)(ws + (size_t)16777216);                    // f16 partials x4 (8 MB each)
  __half* p1 = p0 + 4194304;
  __half* p2 = p1 + 4194304;
  __half* p3 = p2 + 4194304;
  const size_t need4 = 16777216ULL + 4ULL * 8388608ULL;

  hipFuncSetAttribute(reinterpret_cast<const void*>(k_attn),
                      hipFuncAttributeMaxDynamicSharedMemorySize, 131072);

  k_nxgx<<<dim3(PN / 64, BN), 256, 0, stream>>>(x, Wm, bias, xnK, gxF);
  if (ws_size >= need4) {
    k_attn<<<dim3(256), 512, 131072, stream>>>(xnK, gxF, p0, p1, p2, p3, 2, (PN / 4) / QT);
    k_add<<<dim3(2048), 256, 0, stream>>>(out, (const uint2*)p0, (const uint2*)p1,
                                          (const uint2*)p2, (const uint2*)p3, 4, BN * CN * PN / 4);
  } else {
    k_attn<<<dim3(128), 512, 131072, stream>>>(xnK, gxF, p0, p1, p0, p1, 1, (PN / 2) / QT);
    k_add<<<dim3(2048), 256, 0, stream>>>(out, (const uint2*)p0, (const uint2*)p1,
                                          (const uint2*)p0, (const uint2*)p1, 2, BN * CN * PN / 4);
  }
}